// Round 1
// baseline (168.759 us; speedup 1.0000x reference)
//
#include <hip/hip_runtime.h>

#define NN 100000
#define OUT_DIM 128

// --- kernel 1: zero the per-node max array; block 0 also computes mean(W_phi)
__global__ void init_kernel(float* __restrict__ maxd, float* __restrict__ meanW,
                            const float* __restrict__ W_phi, int n) {
    int i = blockIdx.x * blockDim.x + threadIdx.x;
    if (i < n) maxd[i] = 0.0f;
    if (blockIdx.x == 0 && threadIdx.x == 0) {
        float s = 0.0f;
        #pragma unroll
        for (int j = 0; j < OUT_DIM; ++j) s += W_phi[j];
        *meanW = s / (float)OUT_DIM;
    }
}

// --- kernel 2: per-edge projected distance, per-node atomic max
__global__ void edge_kernel(const float* __restrict__ nodes,
                            const int* __restrict__ row,
                            const int* __restrict__ col,
                            const float* __restrict__ Wt,
                            float* __restrict__ maxd, int E) {
    int e = blockIdx.x * blockDim.x + threadIdx.x;
    if (e >= E) return;
    const float w0 = Wt[0], w1 = Wt[1], w2 = Wt[2];
    int r = row[e];
    int c = col[e];
    float dx = nodes[3 * r + 0] - nodes[3 * c + 0];
    float dy = nodes[3 * r + 1] - nodes[3 * c + 1];
    float dz = nodes[3 * r + 2] - nodes[3 * c + 2];
    float d = fabsf(dx * w0 + dy * w1 + dz * w2);
    // maxd values are all >= 0, so int-bit-pattern compare == float compare.
    // Plain-read guard: maxd only grows; a stale (smaller) read just means an
    // extra atomic, never a missed update.
    if (d > maxd[r]) {
        atomicMax((int*)&maxd[r], __float_as_int(d));
    }
}

// --- kernel 3: final combine
__global__ void final_kernel(const float* __restrict__ prev,
                             const float* __restrict__ maxd,
                             const float* __restrict__ meanW,
                             float* __restrict__ out, int n) {
    int i = blockIdx.x * blockDim.x + threadIdx.x;
    if (i < n) {
        out[i] = 0.5f * (prev[i] + (*meanW) * maxd[i]);
    }
}

extern "C" void kernel_launch(void* const* d_in, const int* in_sizes, int n_in,
                              void* d_out, int out_size, void* d_ws, size_t ws_size,
                              hipStream_t stream) {
    const float* prev   = (const float*)d_in[0];   // [N]
    const float* nodes  = (const float*)d_in[1];   // [N,3]
    const int*   row    = (const int*)d_in[2];     // [E]
    const int*   col    = (const int*)d_in[3];     // [E]
    const float* W_phi  = (const float*)d_in[4];   // [128]
    const float* W_theta= (const float*)d_in[5];   // [3]

    const int N = in_sizes[0];
    const int E = in_sizes[2];

    float* maxd  = (float*)d_ws;          // N floats
    float* meanW = (float*)d_ws + N;      // 1 float

    float* out = (float*)d_out;

    const int B = 256;
    init_kernel<<<(N + B - 1) / B, B, 0, stream>>>(maxd, meanW, W_phi, N);
    edge_kernel<<<(E + B - 1) / B, B, 0, stream>>>(nodes, row, col, W_theta, maxd, E);
    final_kernel<<<(N + B - 1) / B, B, 0, stream>>>(prev, maxd, meanW, out, N);
}